// Round 8
// baseline (327.066 us; speedup 1.0000x reference)
//
#include <hip/hip_runtime.h>
#include <hip/hip_bf16.h>

// Problem constants (B=1, H=W=64, C=768, nh=12, hd=64)
#define S_TOK 4096
#define CDIM  768
#define N3C   2304
#define NH    12
#define HD    64

#define LOG2E 1.44269504f

typedef __attribute__((ext_vector_type(8))) short short8;
typedef __attribute__((ext_vector_type(4))) short short4v;
typedef __attribute__((ext_vector_type(4))) float float4v;

__device__ __forceinline__ float b2f(short s) {
    return __uint_as_float(((unsigned)(unsigned short)s) << 16);
}
__device__ __forceinline__ short f2b(float f) {   // round-to-nearest-even
    unsigned u = __float_as_uint(f);
    unsigned r = (u + 0x7FFFu + ((u >> 16) & 1u)) >> 16;
    return (short)r;
}

#if __has_builtin(__builtin_amdgcn_exp2f)
#define EXP2F __builtin_amdgcn_exp2f
#else
#define EXP2F exp2f
#endif

// pack hi16(u1)|hi16(u0) -> one bf16 pair (truncation) via v_perm
__device__ __forceinline__ unsigned pack_trunc(float a, float b) {
    return __builtin_amdgcn_perm(__float_as_uint(b), __float_as_uint(a), 0x07060302u);
}

// ---------------------------------------------------------------------------
// Elementwise fp32 -> bf16 cast (4 elems/thread)
// ---------------------------------------------------------------------------
__global__ __launch_bounds__(256) void cast_bf16_kernel(
    const float* __restrict__ in, short* __restrict__ out, int n4)
{
    int i = blockIdx.x * 256 + threadIdx.x;
    if (i >= n4) return;
    float4 v = ((const float4*)in)[i];
    short4v o4 = { f2b(v.x), f2b(v.y), f2b(v.z), f2b(v.w) };
    *(short4v*)&out[(size_t)i * 4] = o4;
}

// ---------------------------------------------------------------------------
// Transpose + cast: in fp32 [R][C] -> out bf16 [C][R]. 64x64 tiles, 256 thr.
// ---------------------------------------------------------------------------
__global__ __launch_bounds__(256) void transpose_cast_kernel(
    const float* __restrict__ in, short* __restrict__ out, int R, int C)
{
    __shared__ float t[64][65];
    const int tid = threadIdx.x;
    const int c0 = blockIdx.x * 64, r0 = blockIdx.y * 64;
    const int li = tid >> 6;      // 0..3
    const int lj = tid & 63;
#pragma unroll
    for (int p = 0; p < 16; ++p) {
        int i = p * 4 + li;
        t[i][lj] = in[(size_t)(r0 + i) * C + c0 + lj];
    }
    __syncthreads();
#pragma unroll
    for (int p = 0; p < 16; ++p) {
        int i = p * 4 + li;
        out[(size_t)(c0 + i) * R + r0 + lj] = f2b(t[lj][i]);
    }
}

// ---------------------------------------------------------------------------
// MFMA GEMM core: C[128x128] = A[128xK] @ Bt[128xK]^T
// ---------------------------------------------------------------------------
#define GEMM_CORE(A_, Bt_)                                                     \
    __shared__ __align__(16) short a_s[128][72];                               \
    __shared__ __align__(16) short b_s[128][72];                               \
    const int tid  = threadIdx.x;                                              \
    const int m0 = blockIdx.y * 128;                                           \
    const int n0 = blockIdx.x * 128;                                           \
    const int lane = tid & 63, w = tid >> 6;                                   \
    const int l15 = lane & 15, quad = lane >> 4;                               \
    const int wr = w >> 1, wc = w & 1;                                         \
    const int srow = tid >> 1;                                                 \
    const int scol = (tid & 1) * 32;                                           \
    float4v acc[4][4];                                                         \
    _Pragma("unroll")                                                          \
    for (int i = 0; i < 4; ++i)                                                \
        _Pragma("unroll")                                                      \
        for (int j = 0; j < 4; ++j) acc[i][j] = (float4v){0.f,0.f,0.f,0.f};    \
    for (int k0 = 0; k0 < 768; k0 += 64) {                                     \
        __syncthreads();                                                       \
        const short* ga = A_ + (size_t)(m0 + srow) * 768 + k0 + scol;          \
        const short* gb = Bt_ + (size_t)(n0 + srow) * 768 + k0 + scol;         \
        _Pragma("unroll")                                                      \
        for (int v = 0; v < 4; ++v) {                                          \
            *(uint4*)&a_s[srow][scol + v*8] = *(const uint4*)(ga + v*8);       \
            *(uint4*)&b_s[srow][scol + v*8] = *(const uint4*)(gb + v*8);       \
        }                                                                      \
        __syncthreads();                                                       \
        _Pragma("unroll")                                                      \
        for (int kk = 0; kk < 64; kk += 32) {                                  \
            short8 af[4], bfr[4];                                              \
            _Pragma("unroll")                                                  \
            for (int i = 0; i < 4; ++i)                                        \
                af[i] = *(const short8*)&a_s[wr*64 + i*16 + l15][kk + quad*8]; \
            _Pragma("unroll")                                                  \
            for (int j = 0; j < 4; ++j)                                        \
                bfr[j] = *(const short8*)&b_s[wc*64 + j*16 + l15][kk + quad*8];\
            _Pragma("unroll")                                                  \
            for (int i = 0; i < 4; ++i)                                        \
                _Pragma("unroll")                                              \
                for (int j = 0; j < 4; ++j)                                    \
                    acc[i][j] = __builtin_amdgcn_mfma_f32_16x16x32_bf16(       \
                        af[i], bfr[j], acc[i][j], 0, 0, 0);                    \
        }                                                                      \
    }

// QKV GEMM: writes Qb[head][s][d], Kb[head][s][d], Vt[head][d][s] (bf16)
__global__ __launch_bounds__(256) void gemm_qkv_mfma(
    const short* __restrict__ A, const short* __restrict__ Bt,
    const float* __restrict__ bias,
    short* __restrict__ Qb, short* __restrict__ Kb, short* __restrict__ Vt)
{
    GEMM_CORE(A, Bt)

    const int sec = n0 / CDIM;      // tile fully inside one of q/k/v
    float bj[4];
#pragma unroll
    for (int j = 0; j < 4; ++j) bj[j] = bias[n0 + wc*64 + j*16 + l15];

    if (sec < 2) {
        short* dst = (sec == 0) ? Qb : Kb;
#pragma unroll
        for (int i = 0; i < 4; ++i)
#pragma unroll
            for (int j = 0; j < 4; ++j) {
                const int nn = (n0 + wc*64 + j*16 + l15) % CDIM;
                const int head = nn >> 6, d = nn & 63;
#pragma unroll
                for (int r = 0; r < 4; ++r) {
                    const int s = m0 + wr*64 + i*16 + quad*4 + r;
                    dst[((size_t)head * S_TOK + s) * HD + d] = f2b(acc[i][j][r] + bj[j]);
                }
            }
    } else {
#pragma unroll
        for (int i = 0; i < 4; ++i)
#pragma unroll
            for (int j = 0; j < 4; ++j) {
                const int nn = (n0 + wc*64 + j*16 + l15) % CDIM;
                const int head = nn >> 6, d = nn & 63;
                const int sbase = m0 + wr*64 + i*16 + quad*4;
                short4v v4;
#pragma unroll
                for (int r = 0; r < 4; ++r) v4[r] = f2b(acc[i][j][r] + bj[j]);
                *(short4v*)&Vt[((size_t)head * HD + d) * S_TOK + sbase] = v4;
            }
    }
}

// Proj GEMM: out fp32 [4096][768] = A @ Bt^T + bias
__global__ __launch_bounds__(256) void gemm_proj_mfma(
    const short* __restrict__ A, const short* __restrict__ Bt,
    const float* __restrict__ bias, float* __restrict__ out)
{
    GEMM_CORE(A, Bt)

    float bj[4];
#pragma unroll
    for (int j = 0; j < 4; ++j) bj[j] = bias[n0 + wc*64 + j*16 + l15];

#pragma unroll
    for (int i = 0; i < 4; ++i)
#pragma unroll
        for (int j = 0; j < 4; ++j) {
            const int n = n0 + wc*64 + j*16 + l15;
#pragma unroll
            for (int r = 0; r < 4; ++r) {
                const int s = m0 + wr*64 + i*16 + quad*4 + r;
                out[(size_t)s * CDIM + n] = acc[i][j][r] + bj[j];
            }
        }
}

// ---------------------------------------------------------------------------
// Rel-pos tables via MFMA. One block per (y, head); 64 queries s0=y*64..+63.
// Outputs are PRE-SCALED by log2e (flash computes softmax in exp2 domain).
// ---------------------------------------------------------------------------
__global__ __launch_bounds__(256) void rel_mfma_kernel(
    const short* __restrict__ Qb, const float* __restrict__ rph,
    const float* __restrict__ rpw, short* __restrict__ Relh,
    short* __restrict__ Relw)
{
    __shared__ __align__(16) short q_s [64][72];
    __shared__ __align__(16) short rh_s[64][72];
    __shared__ __align__(16) short rw_s[128][72];

    const int tid  = threadIdx.x;
    const int y    = blockIdx.x;
    const int head = blockIdx.y;
    const int s0   = y * 64;
    const int w = tid >> 6, lane = tid & 63;
    const int l15 = lane & 15, quad = lane >> 4;
    const int srow = tid >> 2;            // 0..63
    const int scol = (tid & 3) << 4;      // 0,16,32,48

    // ---- stage Q (bf16 passthrough) ----
    {
        const uint4* g = (const uint4*)(Qb + ((size_t)head * S_TOK + s0 + srow) * HD + scol);
        *(uint4*)&q_s[srow][scol]     = g[0];
        *(uint4*)&q_s[srow][scol + 8] = g[1];
    }
    // ---- stage rph rows y..y+63 (fp32 -> bf16) ----
    {
        const float* g = rph + (size_t)(y + srow) * HD + scol;
        short tmp[16];
#pragma unroll
        for (int i = 0; i < 16; i += 4) {
            float4 v = *(const float4*)(g + i);
            tmp[i] = f2b(v.x); tmp[i+1] = f2b(v.y); tmp[i+2] = f2b(v.z); tmp[i+3] = f2b(v.w);
        }
        *(short8*)&rh_s[srow][scol]     = *(short8*)&tmp[0];
        *(short8*)&rh_s[srow][scol + 8] = *(short8*)&tmp[8];
    }
    // ---- stage rpw rows 0..127 (row 127 clamped; never consumed) ----
#pragma unroll
    for (int half = 0; half < 2; ++half) {
        const int row = srow + half * 64;
        const int rr  = row > 126 ? 126 : row;
        const float* g = rpw + (size_t)rr * HD + scol;
        short tmp[16];
#pragma unroll
        for (int i = 0; i < 16; i += 4) {
            float4 v = *(const float4*)(g + i);
            tmp[i] = f2b(v.x); tmp[i+1] = f2b(v.y); tmp[i+2] = f2b(v.z); tmp[i+3] = f2b(v.w);
        }
        *(short8*)&rw_s[row][scol]     = *(short8*)&tmp[0];
        *(short8*)&rw_s[row][scol + 8] = *(short8*)&tmp[8];
    }
    __syncthreads();

    const short8 qa0 = *(const short8*)&q_s[w * 16 + l15][quad * 8];
    const short8 qa1 = *(const short8*)&q_s[w * 16 + l15][32 + quad * 8];

    // ---- relh: RH col j = y+jj, ky = 63-jj ----
#pragma unroll
    for (int ct = 0; ct < 4; ++ct) {
        const int jj = ct * 16 + l15;
        short8 b0 = *(const short8*)&rh_s[jj][quad * 8];
        short8 b1 = *(const short8*)&rh_s[jj][32 + quad * 8];
        float4v z = (float4v){0.f, 0.f, 0.f, 0.f};
        z = __builtin_amdgcn_mfma_f32_16x16x32_bf16(qa0, b0, z, 0, 0, 0);
        z = __builtin_amdgcn_mfma_f32_16x16x32_bf16(qa1, b1, z, 0, 0, 0);
        const int ky = 63 - jj;
#pragma unroll
        for (int r = 0; r < 4; ++r) {
            const int q = w * 16 + quad * 4 + r;
            Relh[((size_t)head * S_TOK + s0 + q) * HD + ky] = f2b(z[r] * LOG2E);
        }
    }

    // ---- relw: kx = q+63-j, keep 0<=kx<64 ----
#pragma unroll
    for (int ct = 0; ct < 8; ++ct) {
        const int j = ct * 16 + l15;
        short8 b0 = *(const short8*)&rw_s[j][quad * 8];
        short8 b1 = *(const short8*)&rw_s[j][32 + quad * 8];
        float4v z = (float4v){0.f, 0.f, 0.f, 0.f};
        z = __builtin_amdgcn_mfma_f32_16x16x32_bf16(qa0, b0, z, 0, 0, 0);
        z = __builtin_amdgcn_mfma_f32_16x16x32_bf16(qa1, b1, z, 0, 0, 0);
#pragma unroll
        for (int r = 0; r < 4; ++r) {
            const int q  = w * 16 + quad * 4 + r;
            const int kx = q + 63 - j;
            if (kx >= 0 && kx < 64)
                Relw[((size_t)head * S_TOK + s0 + q) * HD + kx] = f2b(z[r] * LOG2E);
        }
    }
}

// ---------------------------------------------------------------------------
// Flash attention v3: barrier-free K-loop, wave-owns-keys split.
// One block per (y, head): 64 queries. Chunk = 128 keys; wave w owns keys
// [w*32, w*32+32) of each chunk. 32 chunks.
//   - S^T = K·Q^T per wave: A = own K rows (GLOBAL->A-frags, no LDS),
//     B = all 64 Q rows in registers (loaded once).
//   - P^T exits in C-layout -> contiguous b64 store into WAVE-PRIVATE LDS
//     [64 q][40 k-pad] (conflict-free) -> b128 B-frags for PV. No barriers.
//   - PV: O^T[d][q] += V^T(global A-frags) · P; denom via ones-A MFMA.
//   - end: 2-buffer tree reduction over the 4 wave-partials (redB overlays
//     the dead P region), then normalize + bf16 store.
// ---------------------------------------------------------------------------
__global__ __launch_bounds__(256, 3) void flash_kernel(
    const short* __restrict__ Qb, const short* __restrict__ Kb,
    const short* __restrict__ Vt, const short* __restrict__ Relh,
    const short* __restrict__ Relw, short* __restrict__ attn_b)
{
    __shared__ __align__(16) short relw_s[64][72];   // [q][kx] bf16 (x log2e)
    __shared__ __align__(16) short pw_s[4][64][40];  // per-wave P [q][k32+pad]
    __shared__ __align__(16) float redA[65][68];     // O^T reduce + denom row

    const int tid  = threadIdx.x;
    const int head = blockIdx.y;
    const int s0   = blockIdx.x * 64;
    const int w    = tid >> 6, lane = tid & 63;
    const int l15  = lane & 15, quad = lane >> 4;
    const int srow = tid >> 2, scol = (tid & 3) << 4;

    const float C1 = 0.125f * LOG2E;

    // ---- stage Relw tile (read cross-wave -> one barrier) ----
    {
        const uint4* g = (const uint4*)(Relw + ((size_t)head * S_TOK + s0 + srow) * HD + scol);
        *(uint4*)&relw_s[srow][scol]     = g[0];
        *(uint4*)&relw_s[srow][scol + 8] = g[1];
    }

    // ---- all 64 Q rows as B-frags (loaded once, 32 VGPRs) ----
    short8 qbf[4][2];
    {
        const short* qbase = Qb + ((size_t)head * S_TOK + s0) * HD;
#pragma unroll
        for (int qt = 0; qt < 4; ++qt)
#pragma unroll
            for (int h = 0; h < 2; ++h)
                qbf[qt][h] = *(const short8*)(qbase + (qt * 16 + l15) * HD + h * 32 + quad * 8);
    }
    __syncthreads();

    short8 aones;
#pragma unroll
    for (int j = 0; j < 8; ++j) aones[j] = (short)0x3F80;

    float4v od[4][4];                  // O^T tiles [dt][qt]
#pragma unroll
    for (int dt = 0; dt < 4; ++dt)
#pragma unroll
        for (int qt = 0; qt < 4; ++qt) od[dt][qt] = (float4v){0.f, 0.f, 0.f, 0.f};
    float4v dq[4];                     // denom per qt (rows equal)
#pragma unroll
    for (int qt = 0; qt < 4; ++qt) dq[qt] = (float4v){0.f, 0.f, 0.f, 0.f};

    const short* kbh = Kb + (size_t)head * S_TOK * HD;
    const short* vbh = Vt + (size_t)head * HD * S_TOK;
    const short* rhh = Relh + ((size_t)head * S_TOK + s0) * HD;
    const int hi = w >> 1;             // high-64 half flag for rh column

    for (int ic = 0; ic < 32; ++ic) {
        const int t0 = ic * 128;

        // rh: column ic*2 + hi of the pre-gathered Relh rows (uniform/wave)
        float rhv[4];
#pragma unroll
        for (int qt = 0; qt < 4; ++qt)
            rhv[qt] = b2f(rhh[(qt * 16 + l15) * HD + ic * 2 + hi]);

        // ---- QK^T (transposed) + exp2 + P store, per 16-key subtile ----
#pragma unroll
        for (int kt = 0; kt < 2; ++kt) {
            const int krow = t0 + w * 32 + kt * 16 + l15;
            const short8 ka0 = *(const short8*)(kbh + (size_t)krow * HD + quad * 8);
            const short8 ka1 = *(const short8*)(kbh + (size_t)krow * HD + 32 + quad * 8);
            const int kxb = (w * 32 + kt * 16) & 63;

#pragma unroll
            for (int qt = 0; qt < 4; ++qt) {
                float4v z = (float4v){0.f, 0.f, 0.f, 0.f};
                z = __builtin_amdgcn_mfma_f32_16x16x32_bf16(ka0, qbf[qt][0], z, 0, 0, 0);
                z = __builtin_amdgcn_mfma_f32_16x16x32_bf16(ka1, qbf[qt][1], z, 0, 0, 0);
                // lane holds S^T[key = quad*4+r][q = l15]
                short4v rw4 = *(const short4v*)&relw_s[qt * 16 + l15][kxb + quad * 4];
                float p0 = EXP2F(C1 * z[0] + rhv[qt] + b2f(rw4[0]));
                float p1 = EXP2F(C1 * z[1] + rhv[qt] + b2f(rw4[1]));
                float p2 = EXP2F(C1 * z[2] + rhv[qt] + b2f(rw4[2]));
                float p3 = EXP2F(C1 * z[3] + rhv[qt] + b2f(rw4[3]));
                uint2 pk;
                pk.x = pack_trunc(p0, p1);
                pk.y = pack_trunc(p2, p3);
                *(uint2*)&pw_s[w][qt * 16 + l15][kt * 16 + quad * 4] = pk;
            }
        }

        // ---- P B-frags (wave-private round trip; lgkmcnt only) ----
        short8 pbf[4];
#pragma unroll
        for (int qt = 0; qt < 4; ++qt)
            pbf[qt] = *(const short8*)&pw_s[w][qt * 16 + l15][quad * 8];

        // ---- PV: O^T += V^T · P ; denom += ones · P ----
#pragma unroll
        for (int dt = 0; dt < 4; ++dt) {
            const short8 va = *(const short8*)(vbh + (size_t)(dt * 16 + l15) * S_TOK
                                               + t0 + w * 32 + quad * 8);
#pragma unroll
            for (int qt = 0; qt < 4; ++qt)
                od[dt][qt] = __builtin_amdgcn_mfma_f32_16x16x32_bf16(va, pbf[qt], od[dt][qt], 0, 0, 0);
        }
#pragma unroll
        for (int qt = 0; qt < 4; ++qt)
            dq[qt] = __builtin_amdgcn_mfma_f32_16x16x32_bf16(aones, pbf[qt], dq[qt], 0, 0, 0);
    }

    // ================= cross-wave reduction =================
    __syncthreads();   // all PV reads of pw_s done before redB overlay
    float (*redB)[68] = (float(*)[68]) & pw_s[0][0][0];   // 17.7 KB <= 20 KB

    if (w == 0 || w == 2) {
        float (*buf)[68] = (w == 0) ? redA : redB;
#pragma unroll
        for (int dt = 0; dt < 4; ++dt)
#pragma unroll
            for (int qt = 0; qt < 4; ++qt)
#pragma unroll
                for (int r = 0; r < 4; ++r)
                    buf[dt * 16 + quad * 4 + r][qt * 16 + l15] = od[dt][qt][r];
        if (quad == 0) {
#pragma unroll
            for (int qt = 0; qt < 4; ++qt)
                buf[64][qt * 16 + l15] = dq[qt][0];
        }
    }
    __syncthreads();
    if (w == 1 || w == 3) {
        float (*buf)[68] = (w == 1) ? redA : redB;
#pragma unroll
        for (int dt = 0; dt < 4; ++dt)
#pragma unroll
            for (int qt = 0; qt < 4; ++qt)
#pragma unroll
                for (int r = 0; r < 4; ++r)
                    buf[dt * 16 + quad * 4 + r][qt * 16 + l15] += od[dt][qt][r];
        if (quad == 0) {
#pragma unroll
            for (int qt = 0; qt < 4; ++qt)
                buf[64][qt * 16 + l15] += dq[qt][0];
        }
    }
    __syncthreads();

    // ---- final: combine halves, normalize, bf16 store ----
    {
        const int q = tid & 63, dg = tid >> 6;
        const float inv = 1.f / (redA[64][q] + redB[64][q]);
        short vs[16];
#pragma unroll
        for (int i = 0; i < 16; ++i) {
            const int d = dg * 16 + i;
            vs[i] = f2b((redA[d][q] + redB[d][q]) * inv);
        }
        short* outp = attn_b + (size_t)(s0 + q) * CDIM + head * HD + dg * 16;
        *(uint4*)outp       = *(uint4*)&vs[0];
        *(uint4*)(outp + 8) = *(uint4*)&vs[8];
    }
}

// ---------------------------------------------------------------------------
extern "C" void kernel_launch(void* const* d_in, const int* in_sizes, int n_in,
                              void* d_out, int out_size, void* d_ws, size_t ws_size,
                              hipStream_t stream)
{
    const float* x    = (const float*)d_in[0];
    const float* qkvw = (const float*)d_in[1];
    const float* qkvb = (const float*)d_in[2];
    const float* rph  = (const float*)d_in[3];
    const float* rpw  = (const float*)d_in[4];
    const float* pw   = (const float*)d_in[5];
    const float* pb   = (const float*)d_in[6];
    float* out = (float*)d_out;

    // ws layout (shorts), total ~48.8 MB
    const size_t HSD = (size_t)NH * S_TOK * HD;   // 3,145,728
    short* xb     = (short*)d_ws;                 // 4096*768
    short* wt     = xb + (size_t)S_TOK * CDIM;    // 2304*768 (qkv_w^T)
    short* pwt    = wt + (size_t)N3C * CDIM;      // 768*768  (proj_w^T)
    short* Qb     = pwt + (size_t)CDIM * CDIM;
    short* Kb     = Qb + HSD;
    short* Vt     = Kb + HSD;
    short* Relh   = Vt + HSD;
    short* Relw   = Relh + HSD;
    short* attn_b = Relw + HSD;                   // 4096*768

    cast_bf16_kernel<<<S_TOK * CDIM / 4 / 256, 256, 0, stream>>>(x, xb, S_TOK * CDIM / 4);
    transpose_cast_kernel<<<dim3(N3C / 64, CDIM / 64), 256, 0, stream>>>(qkvw, wt, CDIM, N3C);
    transpose_cast_kernel<<<dim3(CDIM / 64, CDIM / 64), 256, 0, stream>>>(pw, pwt, CDIM, CDIM);

    gemm_qkv_mfma<<<dim3(N3C / 128, S_TOK / 128), 256, 0, stream>>>(
        xb, wt, qkvb, Qb, Kb, Vt);
    rel_mfma_kernel<<<dim3(64, NH), 256, 0, stream>>>(Qb, rph, rpw, Relh, Relw);
    flash_kernel<<<dim3(64, NH), 256, 0, stream>>>(Qb, Kb, Vt, Relh, Relw, attn_b);
    gemm_proj_mfma<<<dim3(CDIM / 128, S_TOK / 128), 256, 0, stream>>>(
        attn_b, pwt, pb, out);
}

// Round 9
// 248.329 us; speedup vs baseline: 1.3171x; 1.3171x over previous
//
#include <hip/hip_runtime.h>
#include <hip/hip_bf16.h>

// Problem constants (B=1, H=W=64, C=768, nh=12, hd=64)
#define S_TOK 4096
#define CDIM  768
#define N3C   2304
#define NH    12
#define HD    64

#define LOG2E 1.44269504f

typedef __attribute__((ext_vector_type(8))) short short8;
typedef __attribute__((ext_vector_type(4))) short short4v;
typedef __attribute__((ext_vector_type(4))) float float4v;

__device__ __forceinline__ float b2f(short s) {
    return __uint_as_float(((unsigned)(unsigned short)s) << 16);
}
__device__ __forceinline__ short f2b(float f) {   // round-to-nearest-even
    unsigned u = __float_as_uint(f);
    unsigned r = (u + 0x7FFFu + ((u >> 16) & 1u)) >> 16;
    return (short)r;
}

#if __has_builtin(__builtin_amdgcn_exp2f)
#define EXP2F __builtin_amdgcn_exp2f
#else
#define EXP2F exp2f
#endif

// pack trunc-bf16(a) into low short, trunc-bf16(b) into high short
__device__ __forceinline__ unsigned pack_trunc(float a, float b) {
    return __builtin_amdgcn_perm(__float_as_uint(b), __float_as_uint(a), 0x07060302u);
}

// ---------------------------------------------------------------------------
// Elementwise fp32 -> bf16 cast (4 elems/thread)
// ---------------------------------------------------------------------------
__global__ __launch_bounds__(256) void cast_bf16_kernel(
    const float* __restrict__ in, short* __restrict__ out, int n4)
{
    int i = blockIdx.x * 256 + threadIdx.x;
    if (i >= n4) return;
    float4 v = ((const float4*)in)[i];
    short4v o4 = { f2b(v.x), f2b(v.y), f2b(v.z), f2b(v.w) };
    *(short4v*)&out[(size_t)i * 4] = o4;
}

// ---------------------------------------------------------------------------
// Transpose + cast: in fp32 [R][C] -> out bf16 [C][R]. 64x64 tiles, 256 thr.
// ---------------------------------------------------------------------------
__global__ __launch_bounds__(256) void transpose_cast_kernel(
    const float* __restrict__ in, short* __restrict__ out, int R, int C)
{
    __shared__ float t[64][65];
    const int tid = threadIdx.x;
    const int c0 = blockIdx.x * 64, r0 = blockIdx.y * 64;
    const int li = tid >> 6;      // 0..3
    const int lj = tid & 63;
#pragma unroll
    for (int p = 0; p < 16; ++p) {
        int i = p * 4 + li;
        t[i][lj] = in[(size_t)(r0 + i) * C + c0 + lj];
    }
    __syncthreads();
#pragma unroll
    for (int p = 0; p < 16; ++p) {
        int i = p * 4 + li;
        out[(size_t)(c0 + i) * R + r0 + lj] = f2b(t[lj][i]);
    }
}

// ---------------------------------------------------------------------------
// MFMA GEMM core: C[128x128] = A[128xK] @ Bt[128xK]^T
// ---------------------------------------------------------------------------
#define GEMM_CORE(A_, Bt_)                                                     \
    __shared__ __align__(16) short a_s[128][72];                               \
    __shared__ __align__(16) short b_s[128][72];                               \
    const int tid  = threadIdx.x;                                              \
    const int m0 = blockIdx.y * 128;                                           \
    const int n0 = blockIdx.x * 128;                                           \
    const int lane = tid & 63, w = tid >> 6;                                   \
    const int l15 = lane & 15, quad = lane >> 4;                               \
    const int wr = w >> 1, wc = w & 1;                                         \
    const int srow = tid >> 1;                                                 \
    const int scol = (tid & 1) * 32;                                           \
    float4v acc[4][4];                                                         \
    _Pragma("unroll")                                                          \
    for (int i = 0; i < 4; ++i)                                                \
        _Pragma("unroll")                                                      \
        for (int j = 0; j < 4; ++j) acc[i][j] = (float4v){0.f,0.f,0.f,0.f};    \
    for (int k0 = 0; k0 < 768; k0 += 64) {                                     \
        __syncthreads();                                                       \
        const short* ga = A_ + (size_t)(m0 + srow) * 768 + k0 + scol;          \
        const short* gb = Bt_ + (size_t)(n0 + srow) * 768 + k0 + scol;         \
        _Pragma("unroll")                                                      \
        for (int v = 0; v < 4; ++v) {                                          \
            *(uint4*)&a_s[srow][scol + v*8] = *(const uint4*)(ga + v*8);       \
            *(uint4*)&b_s[srow][scol + v*8] = *(const uint4*)(gb + v*8);       \
        }                                                                      \
        __syncthreads();                                                       \
        _Pragma("unroll")                                                      \
        for (int kk = 0; kk < 64; kk += 32) {                                  \
            short8 af[4], bfr[4];                                              \
            _Pragma("unroll")                                                  \
            for (int i = 0; i < 4; ++i)                                        \
                af[i] = *(const short8*)&a_s[wr*64 + i*16 + l15][kk + quad*8]; \
            _Pragma("unroll")                                                  \
            for (int j = 0; j < 4; ++j)                                        \
                bfr[j] = *(const short8*)&b_s[wc*64 + j*16 + l15][kk + quad*8];\
            _Pragma("unroll")                                                  \
            for (int i = 0; i < 4; ++i)                                        \
                _Pragma("unroll")                                              \
                for (int j = 0; j < 4; ++j)                                    \
                    acc[i][j] = __builtin_amdgcn_mfma_f32_16x16x32_bf16(       \
                        af[i], bfr[j], acc[i][j], 0, 0, 0);                    \
        }                                                                      \
    }

// QKV GEMM: writes Qb[head][s][d], Kb[head][s][d], Vt[head][d][s] (bf16)
__global__ __launch_bounds__(256) void gemm_qkv_mfma(
    const short* __restrict__ A, const short* __restrict__ Bt,
    const float* __restrict__ bias,
    short* __restrict__ Qb, short* __restrict__ Kb, short* __restrict__ Vt)
{
    GEMM_CORE(A, Bt)

    const int sec = n0 / CDIM;      // tile fully inside one of q/k/v
    float bj[4];
#pragma unroll
    for (int j = 0; j < 4; ++j) bj[j] = bias[n0 + wc*64 + j*16 + l15];

    if (sec < 2) {
        short* dst = (sec == 0) ? Qb : Kb;
#pragma unroll
        for (int i = 0; i < 4; ++i)
#pragma unroll
            for (int j = 0; j < 4; ++j) {
                const int nn = (n0 + wc*64 + j*16 + l15) % CDIM;
                const int head = nn >> 6, d = nn & 63;
#pragma unroll
                for (int r = 0; r < 4; ++r) {
                    const int s = m0 + wr*64 + i*16 + quad*4 + r;
                    dst[((size_t)head * S_TOK + s) * HD + d] = f2b(acc[i][j][r] + bj[j]);
                }
            }
    } else {
#pragma unroll
        for (int i = 0; i < 4; ++i)
#pragma unroll
            for (int j = 0; j < 4; ++j) {
                const int nn = (n0 + wc*64 + j*16 + l15) % CDIM;
                const int head = nn >> 6, d = nn & 63;
                const int sbase = m0 + wr*64 + i*16 + quad*4;
                short4v v4;
#pragma unroll
                for (int r = 0; r < 4; ++r) v4[r] = f2b(acc[i][j][r] + bj[j]);
                *(short4v*)&Vt[((size_t)head * HD + d) * S_TOK + sbase] = v4;
            }
    }
}

// Proj GEMM: out fp32 [4096][768] = A @ Bt^T + bias
__global__ __launch_bounds__(256) void gemm_proj_mfma(
    const short* __restrict__ A, const short* __restrict__ Bt,
    const float* __restrict__ bias, float* __restrict__ out)
{
    GEMM_CORE(A, Bt)

    float bj[4];
#pragma unroll
    for (int j = 0; j < 4; ++j) bj[j] = bias[n0 + wc*64 + j*16 + l15];

#pragma unroll
    for (int i = 0; i < 4; ++i)
#pragma unroll
        for (int j = 0; j < 4; ++j) {
            const int n = n0 + wc*64 + j*16 + l15;
#pragma unroll
            for (int r = 0; r < 4; ++r) {
                const int s = m0 + wr*64 + i*16 + quad*4 + r;
                out[(size_t)s * CDIM + n] = acc[i][j][r] + bj[j];
            }
        }
}

// ---------------------------------------------------------------------------
// Rel-pos tables via MFMA. One block per (y, head); 64 queries s0=y*64..+63.
// Outputs are PRE-SCALED by log2e (flash computes softmax in exp2 domain).
// ---------------------------------------------------------------------------
__global__ __launch_bounds__(256) void rel_mfma_kernel(
    const short* __restrict__ Qb, const float* __restrict__ rph,
    const float* __restrict__ rpw, short* __restrict__ Relh,
    short* __restrict__ Relw)
{
    __shared__ __align__(16) short q_s [64][72];
    __shared__ __align__(16) short rh_s[64][72];
    __shared__ __align__(16) short rw_s[128][72];

    const int tid  = threadIdx.x;
    const int y    = blockIdx.x;
    const int head = blockIdx.y;
    const int s0   = y * 64;
    const int w = tid >> 6, lane = tid & 63;
    const int l15 = lane & 15, quad = lane >> 4;
    const int srow = tid >> 2;            // 0..63
    const int scol = (tid & 3) << 4;      // 0,16,32,48

    // ---- stage Q (bf16 passthrough) ----
    {
        const uint4* g = (const uint4*)(Qb + ((size_t)head * S_TOK + s0 + srow) * HD + scol);
        *(uint4*)&q_s[srow][scol]     = g[0];
        *(uint4*)&q_s[srow][scol + 8] = g[1];
    }
    // ---- stage rph rows y..y+63 (fp32 -> bf16) ----
    {
        const float* g = rph + (size_t)(y + srow) * HD + scol;
        short tmp[16];
#pragma unroll
        for (int i = 0; i < 16; i += 4) {
            float4 v = *(const float4*)(g + i);
            tmp[i] = f2b(v.x); tmp[i+1] = f2b(v.y); tmp[i+2] = f2b(v.z); tmp[i+3] = f2b(v.w);
        }
        *(short8*)&rh_s[srow][scol]     = *(short8*)&tmp[0];
        *(short8*)&rh_s[srow][scol + 8] = *(short8*)&tmp[8];
    }
    // ---- stage rpw rows 0..127 (row 127 clamped; never consumed) ----
#pragma unroll
    for (int half = 0; half < 2; ++half) {
        const int row = srow + half * 64;
        const int rr  = row > 126 ? 126 : row;
        const float* g = rpw + (size_t)rr * HD + scol;
        short tmp[16];
#pragma unroll
        for (int i = 0; i < 16; i += 4) {
            float4 v = *(const float4*)(g + i);
            tmp[i] = f2b(v.x); tmp[i+1] = f2b(v.y); tmp[i+2] = f2b(v.z); tmp[i+3] = f2b(v.w);
        }
        *(short8*)&rw_s[row][scol]     = *(short8*)&tmp[0];
        *(short8*)&rw_s[row][scol + 8] = *(short8*)&tmp[8];
    }
    __syncthreads();

    const short8 qa0 = *(const short8*)&q_s[w * 16 + l15][quad * 8];
    const short8 qa1 = *(const short8*)&q_s[w * 16 + l15][32 + quad * 8];

    // ---- relh: RH col j = y+jj, ky = 63-jj ----
#pragma unroll
    for (int ct = 0; ct < 4; ++ct) {
        const int jj = ct * 16 + l15;
        short8 b0 = *(const short8*)&rh_s[jj][quad * 8];
        short8 b1 = *(const short8*)&rh_s[jj][32 + quad * 8];
        float4v z = (float4v){0.f, 0.f, 0.f, 0.f};
        z = __builtin_amdgcn_mfma_f32_16x16x32_bf16(qa0, b0, z, 0, 0, 0);
        z = __builtin_amdgcn_mfma_f32_16x16x32_bf16(qa1, b1, z, 0, 0, 0);
        const int ky = 63 - jj;
#pragma unroll
        for (int r = 0; r < 4; ++r) {
            const int q = w * 16 + quad * 4 + r;
            Relh[((size_t)head * S_TOK + s0 + q) * HD + ky] = f2b(z[r] * LOG2E);
        }
    }

    // ---- relw: kx = q+63-j, keep 0<=kx<64 ----
#pragma unroll
    for (int ct = 0; ct < 8; ++ct) {
        const int j = ct * 16 + l15;
        short8 b0 = *(const short8*)&rw_s[j][quad * 8];
        short8 b1 = *(const short8*)&rw_s[j][32 + quad * 8];
        float4v z = (float4v){0.f, 0.f, 0.f, 0.f};
        z = __builtin_amdgcn_mfma_f32_16x16x32_bf16(qa0, b0, z, 0, 0, 0);
        z = __builtin_amdgcn_mfma_f32_16x16x32_bf16(qa1, b1, z, 0, 0, 0);
#pragma unroll
        for (int r = 0; r < 4; ++r) {
            const int q  = w * 16 + quad * 4 + r;
            const int kx = q + 63 - j;
            if (kx >= 0 && kx < 64)
                Relw[((size_t)head * S_TOK + s0 + q) * HD + kx] = f2b(z[r] * LOG2E);
        }
    }
}

// ---------------------------------------------------------------------------
// Flash attention v2.5: v2's LDS double-buffered staging + S^T orientation.
// One block per (y, head); wave w owns queries [w*16, w*16+16). 64 chunks of
// 64 keys, one barrier per chunk.
//   - S^T = K·Q^T: A-frags = K rows from LDS, B-frags = own 16 Q rows (regs)
//   - per lane: q = w*16+l15 fixed; 4 consecutive keys per (kt) tile
//     -> P stored as packed uint2 (trunc bf16), wave-private, conflict-free
//   - PV: O^T[d][q] += V^T(LDS A-frags) · P(LDS B-frags)
//   - denominator: ones-A MFMA; rows equal -> inv = 1/dq[0], no shuffles
//   - rh: ky == chunk idx -> ONE scalar load/chunk; rw: 16 invariant VGPRs
// ---------------------------------------------------------------------------
__global__ __launch_bounds__(256, 3) void flash_kernel(
    const short* __restrict__ Qb, const short* __restrict__ Kb,
    const short* __restrict__ Vt, const short* __restrict__ Relh,
    const short* __restrict__ Relw, short* __restrict__ attn_b)
{
    __shared__ __align__(16) short k_s [2][64][72];   // [buf][key][d]
    __shared__ __align__(16) short vt_s[2][64][72];   // [buf][d][key]
    __shared__ __align__(16) short p_s [4][16][72];   // per-wave P [q][key]

    const int tid  = threadIdx.x;
    const int head = blockIdx.y;
    const int s0   = blockIdx.x * 64;
    const int w    = tid >> 6, lane = tid & 63;
    const int l15  = lane & 15, quad = lane >> 4;
    const int srow = tid >> 2, scol = (tid & 3) << 4;

    const float C1 = 0.125f * LOG2E;
    const int q = w * 16 + l15;        // this lane's query index (fixed)

    // ---- Q B-frags (16 VGPRs, loaded once from global) ----
    short8 qb0, qb1;
    {
        const short* qrow = Qb + ((size_t)head * S_TOK + s0 + q) * HD;
        qb0 = *(const short8*)(qrow + quad * 8);
        qb1 = *(const short8*)(qrow + 32 + quad * 8);
    }

    // ---- relw -> 16 invariant VGPRs: rw[kt][r], kx = kt*16 + quad*4 + r ----
    float rw[4][4];
    {
        const short* rwrow = Relw + ((size_t)head * S_TOK + s0 + q) * HD;
#pragma unroll
        for (int kt = 0; kt < 4; ++kt) {
            short4v v = *(const short4v*)(rwrow + kt * 16 + quad * 4);
#pragma unroll
            for (int r = 0; r < 4; ++r) rw[kt][r] = b2f(v[r]);
        }
    }

    const short* rhrow = Relh + ((size_t)head * S_TOK + s0 + q) * HD;
    float rh_c = b2f(rhrow[0]);

    // ones A-frag for the denominator
    short8 aones;
#pragma unroll
    for (int j = 0; j < 8; ++j) aones[j] = (short)0x3F80;

    float4v od[4];                     // O^T tiles [dt]: col=q, row=d offset
#pragma unroll
    for (int dt = 0; dt < 4; ++dt) od[dt] = (float4v){0.f, 0.f, 0.f, 0.f};
    float4v dq = (float4v){0.f, 0.f, 0.f, 0.f};

    // ---- stage chunk 0 (same cooperative pattern as the GEMMs) ----
    const short* kbase = Kb + (size_t)head * S_TOK * HD + (size_t)srow * HD + scol;
    const short* vbase = Vt + ((size_t)head * HD + srow) * S_TOK + scol;
    {
        uint4 a = *(const uint4*)(kbase);
        uint4 b = *(const uint4*)(kbase + 8);
        uint4 c = *(const uint4*)(vbase);
        uint4 d = *(const uint4*)(vbase + 8);
        *(uint4*)&k_s[0][srow][scol]      = a;
        *(uint4*)&k_s[0][srow][scol + 8]  = b;
        *(uint4*)&vt_s[0][srow][scol]     = c;
        *(uint4*)&vt_s[0][srow][scol + 8] = d;
    }
    __syncthreads();

    for (int ic = 0; ic < 64; ++ic) {
        const int cur = ic & 1;

        // ---- issue next-chunk prefetch (lands during compute) ----
        uint4 pk0, pk1, pv0, pv1;
        short rhn;
        if (ic < 63) {
            const size_t ko = (size_t)(ic + 1) * 64 * HD;
            const int    vo = (ic + 1) * 64;
            pk0 = *(const uint4*)(kbase + ko);
            pk1 = *(const uint4*)(kbase + ko + 8);
            pv0 = *(const uint4*)(vbase + vo);
            pv1 = *(const uint4*)(vbase + vo + 8);
            rhn = rhrow[ic + 1];
        }

        // ---- S^T per 16-key tile: A=K rows (LDS), B=Q (regs); exp2; pack ----
#pragma unroll
        for (int kt = 0; kt < 4; ++kt) {
            const short8 ka0 = *(const short8*)&k_s[cur][kt * 16 + l15][quad * 8];
            const short8 ka1 = *(const short8*)&k_s[cur][kt * 16 + l15][32 + quad * 8];
            float4v z = (float4v){0.f, 0.f, 0.f, 0.f};
            z = __builtin_amdgcn_mfma_f32_16x16x32_bf16(ka0, qb0, z, 0, 0, 0);
            z = __builtin_amdgcn_mfma_f32_16x16x32_bf16(ka1, qb1, z, 0, 0, 0);
            // lane: key = kt*16 + quad*4 + r, query = l15 (own wave's q)
            float p0 = EXP2F(C1 * z[0] + (rh_c + rw[kt][0]));
            float p1 = EXP2F(C1 * z[1] + (rh_c + rw[kt][1]));
            float p2 = EXP2F(C1 * z[2] + (rh_c + rw[kt][2]));
            float p3 = EXP2F(C1 * z[3] + (rh_c + rw[kt][3]));
            uint2 pk;
            pk.x = pack_trunc(p0, p1);
            pk.y = pack_trunc(p2, p3);
            *(uint2*)&p_s[w][l15][kt * 16 + quad * 4] = pk;
        }

        // ---- P B-frags (wave-private round trip) ----
        const short8 pb0 = *(const short8*)&p_s[w][l15][quad * 8];
        const short8 pb1 = *(const short8*)&p_s[w][l15][32 + quad * 8];

        // ---- PV: O^T[dt] += V^T · P ; denom += ones · P ----
#pragma unroll
        for (int dt = 0; dt < 4; ++dt) {
            const short8 va0 = *(const short8*)&vt_s[cur][dt * 16 + l15][quad * 8];
            const short8 va1 = *(const short8*)&vt_s[cur][dt * 16 + l15][32 + quad * 8];
            od[dt] = __builtin_amdgcn_mfma_f32_16x16x32_bf16(va0, pb0, od[dt], 0, 0, 0);
            od[dt] = __builtin_amdgcn_mfma_f32_16x16x32_bf16(va1, pb1, od[dt], 0, 0, 0);
        }
        dq = __builtin_amdgcn_mfma_f32_16x16x32_bf16(aones, pb0, dq, 0, 0, 0);
        dq = __builtin_amdgcn_mfma_f32_16x16x32_bf16(aones, pb1, dq, 0, 0, 0);

        // ---- store prefetch to the other buffer; single barrier ----
        if (ic < 63) {
            *(uint4*)&k_s[cur ^ 1][srow][scol]      = pk0;
            *(uint4*)&k_s[cur ^ 1][srow][scol + 8]  = pk1;
            *(uint4*)&vt_s[cur ^ 1][srow][scol]     = pv0;
            *(uint4*)&vt_s[cur ^ 1][srow][scol + 8] = pv1;
            rh_c = b2f(rhn);
            __syncthreads();
        }
    }

    // ---- epilogue: denominator rows are equal -> inv per lane; b64 stores ----
    const float inv = 1.f / dq[0];
    short* outp = attn_b + (size_t)(s0 + q) * CDIM + head * HD;
#pragma unroll
    for (int dt = 0; dt < 4; ++dt) {
        short4v o4;
#pragma unroll
        for (int r = 0; r < 4; ++r) o4[r] = f2b(od[dt][r] * inv);
        *(short4v*)(outp + dt * 16 + quad * 4) = o4;
    }
}

// ---------------------------------------------------------------------------
extern "C" void kernel_launch(void* const* d_in, const int* in_sizes, int n_in,
                              void* d_out, int out_size, void* d_ws, size_t ws_size,
                              hipStream_t stream)
{
    const float* x    = (const float*)d_in[0];
    const float* qkvw = (const float*)d_in[1];
    const float* qkvb = (const float*)d_in[2];
    const float* rph  = (const float*)d_in[3];
    const float* rpw  = (const float*)d_in[4];
    const float* pw   = (const float*)d_in[5];
    const float* pb   = (const float*)d_in[6];
    float* out = (float*)d_out;

    // ws layout (shorts), total ~48.8 MB
    const size_t HSD = (size_t)NH * S_TOK * HD;   // 3,145,728
    short* xb     = (short*)d_ws;                 // 4096*768
    short* wt     = xb + (size_t)S_TOK * CDIM;    // 2304*768 (qkv_w^T)
    short* pwt    = wt + (size_t)N3C * CDIM;      // 768*768  (proj_w^T)
    short* Qb     = pwt + (size_t)CDIM * CDIM;
    short* Kb     = Qb + HSD;
    short* Vt     = Kb + HSD;
    short* Relh   = Vt + HSD;
    short* Relw   = Relh + HSD;
    short* attn_b = Relw + HSD;                   // 4096*768

    cast_bf16_kernel<<<S_TOK * CDIM / 4 / 256, 256, 0, stream>>>(x, xb, S_TOK * CDIM / 4);
    transpose_cast_kernel<<<dim3(N3C / 64, CDIM / 64), 256, 0, stream>>>(qkvw, wt, CDIM, N3C);
    transpose_cast_kernel<<<dim3(CDIM / 64, CDIM / 64), 256, 0, stream>>>(pw, pwt, CDIM, CDIM);

    gemm_qkv_mfma<<<dim3(N3C / 128, S_TOK / 128), 256, 0, stream>>>(
        xb, wt, qkvb, Qb, Kb, Vt);
    rel_mfma_kernel<<<dim3(64, NH), 256, 0, stream>>>(Qb, rph, rpw, Relh, Relw);
    flash_kernel<<<dim3(64, NH), 256, 0, stream>>>(Qb, Kb, Vt, Relh, Relw, attn_b);
    gemm_proj_mfma<<<dim3(CDIM / 128, S_TOK / 128), 256, 0, stream>>>(
        attn_b, pwt, pb, out);
}